// Round 5
// baseline (126.702 us; speedup 1.0000x reference)
//
#include <hip/hip_runtime.h>
#include <math.h>

#define C_   128
#define T_   64
#define V_   25
#define TV   1600       // T_*V_
#define CTV  204800     // C_*TV
#define EPS  1e-5f
#define TT   2          // t's per block
#define HS   136        // hT/yT row stride (bf16), 272 B (16B-aligned, 2-way banks)
#define ZS   72         // z row stride (bf16), 144 B (16B-aligned, 2-way banks)

typedef __bf16 bf16x8 __attribute__((ext_vector_type(8)));
typedef float  f32x4  __attribute__((ext_vector_type(4)));

// Exact-enough GELU: erf via Abramowitz-Stegun 7.1.26 (|eps| < 2.5e-7).
__device__ __forceinline__ float gelu_exact(float x) {
  float y = fabsf(x) * 0.70710678118654752440f;
  float t = __builtin_amdgcn_rcpf(fmaf(0.3275911f, y, 1.0f));
  float p = fmaf(1.061405429f, t, -1.453152027f);
  p = fmaf(p, t, 1.421413741f);
  p = fmaf(p, t, -0.284496736f);
  p = fmaf(p, t, 0.254829592f);
  p = p * t;
  float s = p * __expf(-y * y);
  float hxs = 0.5f * x * s;
  return x >= 0.0f ? x - hxs : hxs;
}

// Pack conv weights (BN0 folded into W1) + spatial matrices into MFMA A-frag order.
// A-frag: lane l, elem j -> A[row = l&15][k = (l>>4)*8 + j]
__global__ __launch_bounds__(256) void prep_pack(
    const float* __restrict__ W1, const float* __restrict__ W2,
    const float* __restrict__ topo, const float* __restrict__ spat,
    const float* __restrict__ b1,
    const float* __restrict__ bn0g, const float* __restrict__ bn0b,
    const float* __restrict__ bn0m, const float* __restrict__ bn0v,
    __bf16* __restrict__ W1p, __bf16* __restrict__ W2p, __bf16* __restrict__ Sp,
    float* __restrict__ b1a) {
  if (blockIdx.x == 128) {   // b1a[o] = b1[o] + sum_c W1[o,c]*add0[c]
    int o = threadIdx.x;     // 0..255
    float acc = b1[o];
    for (int c = 0; c < 128; ++c) {
      float inv = bn0g[c] * rsqrtf(bn0v[c] + EPS);
      float add = fmaf(-bn0m[c], inv, bn0b[c]);
      acc = fmaf(W1[o * 128 + c], add, acc);
    }
    b1a[o] = acc;
    return;
  }
  int i = blockIdx.x * 256 + threadIdx.x;
  if (i < 32768) {   // W1p: 16 mt * 4 ks * 64 * 8, scaled by inv0[c]
    int j = i & 7, l = (i >> 3) & 63, ks = (i >> 9) & 3, mt = i >> 11;
    int o = mt * 16 + (l & 15);
    int c = ks * 32 + ((l >> 4) << 3) + j;
    float inv = bn0g[c] * rsqrtf(bn0v[c] + EPS);
    W1p[i] = (__bf16)(W1[o * 128 + c] * inv);
  }
  if (i < 16384) {   // W2p: 8 mt * 4 ks * 64 * 8
    int j = i & 7, l = (i >> 3) & 63, ks = (i >> 9) & 3, mt = i >> 11;
    int o = mt * 16 + (l & 15);
    int c = ks * 32 + ((l >> 4) << 3) + j;
    W2p[i] = (__bf16)W2[o * 128 + c];
  }
  if (i < 8192) {    // Sp: h(4 over 2 blk-idx bits? no: h(2)*mat(2)*mt(2)*64*8) zero-padded
    int j = i & 7, l = (i >> 3) & 63, mt = (i >> 9) & 1, mat = (i >> 10) & 1, h = i >> 11;
    int u = mt * 16 + (l & 15);
    int v = ((l >> 4) << 3) + j;
    const float* src = mat ? spat : topo;
    Sp[i] = (__bf16)((u < 25 && v < 25) ? src[h * 625 + u * 25 + v] : 0.0f);
  }
}

__global__ __launch_bounds__(512, 8) void fused_v5(
    const float* __restrict__ x,
    const float* __restrict__ bn1g, const float* __restrict__ bn1b,
    const float* __restrict__ bn1m, const float* __restrict__ bn1v,
    const float* __restrict__ bn2g, const float* __restrict__ bn2b,
    const float* __restrict__ bn2m, const float* __restrict__ bn2v,
    const float* __restrict__ b2,
    const __bf16* __restrict__ W1p, const __bf16* __restrict__ W2p,
    const __bf16* __restrict__ Sp,  const float* __restrict__ b1a,
    float* __restrict__ out) {
  // Region A: hT (64 rows x HS), later z2 (128 rows x ZS). Region B: z1 (128 x ZS), later yT (64 x HS).
  __shared__ __bf16 sA[9216];              // 18432 B
  __shared__ __bf16 sB[9216];              // 18432 B
  __shared__ float  sInv[256], sAdd[256], sB1a[256], sB2[128];  // 3584 B
  // total 40448 B -> 4 blocks/CU

  const int bt = blockIdx.x;               // 0..4095
  const int b  = bt >> 5;
  const int tb = bt & 31;
  const float* xb = x   + (size_t)b * CTV + tb * (TT * V_);
  float*       ob = out + (size_t)b * CTV + tb * (TT * V_);
  const int tid  = threadIdx.x;
  const int wave = tid >> 6, lane = tid & 63;
  const int lr = lane & 15, lg = lane >> 4;

  // ---------------- P0: tables, pads, x -> bf16 hT in sA ----------------
  if (tid < 256) {
    int o = tid;
    float g, bb, m, vv;
    if (o < 128) { g = bn1g[o]; bb = bn1b[o]; m = bn1m[o]; vv = bn1v[o]; }
    else { int c = o - 128; g = bn2g[c]; bb = bn2b[c]; m = bn2m[c]; vv = bn2v[c]; }
    float inv = g * rsqrtf(vv + EPS);
    sInv[o] = inv;
    sAdd[o] = fmaf(-m, inv, bb);
    sB1a[o] = b1a[o];
    if (o < 128) sB2[o] = b2[o];
  }
  // zero hT pad rows {25..31, 57..63} (14 rows x 17 b128)
  for (int i = tid; i < 238; i += 512) {
    int rowIdx = i / 17, k = i - rowIdx * 17;
    int row = (rowIdx < 7 ? 25 + rowIdx : 50 + rowIdx);
    bf16x8 zz = {};
    *reinterpret_cast<bf16x8*>(sA + row * HS + k * 8) = zz;
  }
  // zero z1 pad cols [24..32) for all (c,t) (col 24 rewritten later, after a barrier)
  if (tid < 256) {
    int c = tid >> 1, t = tid & 1;
    bf16x8 zz = {};
    *reinterpret_cast<bf16x8*>(sB + c * ZS + t * 32 + 24) = zz;
  }
  {
    const int c = tid >> 2, q = tid & 3;
    const int t = q & 1, vh = q >> 1;
    const int v0 = vh ? 13 : 0, v1 = vh ? 25 : 13;
    const float* xr = xb + c * TV + t * V_;
    for (int v = v0; v < v1; ++v)
      sA[(t * 32 + v) * HS + c] = (__bf16)xr[v];
  }
  __syncthreads();   // (1)

  // ---------------- P1: conv1 MFMA (M=256,K=128,N=64) ----------------
  f32x4 acc[2][4] = {};
  {
    #pragma unroll
    for (int ks = 0; ks < 4; ++ks) {
      bf16x8 af[2];
      #pragma unroll
      for (int m2 = 0; m2 < 2; ++m2)
        af[m2] = *reinterpret_cast<const bf16x8*>(W1p + (((wave * 2 + m2) * 4 + ks) << 9) + lane * 8);
      bf16x8 bfr[4];
      #pragma unroll
      for (int n4 = 0; n4 < 4; ++n4)
        bfr[n4] = *reinterpret_cast<const bf16x8*>(&sA[(n4 * 16 + lr) * HS + ks * 32 + lg * 8]);
      #pragma unroll
      for (int m2 = 0; m2 < 2; ++m2)
        #pragma unroll
        for (int n4 = 0; n4 < 4; ++n4)
          acc[m2][n4] = __builtin_amdgcn_mfma_f32_16x16x32_bf16(af[m2], bfr[n4], acc[m2][n4], 0, 0, 0);
    }
  }
  __syncthreads();   // (2) — all hT reads done; sA reusable as z2

  // ---------------- P1 epilogue: GELU + BN1/BN2 -> z1 (sB), z2 (sA) ----------------
  {
    // zero z2 pad cols [25..32) (col 24/56 are valid, written below by epilogue threads)
    if (tid < 256) {
      int c = tid >> 1, t = tid & 1;
      #pragma unroll
      for (int pv = 25; pv < 32; ++pv)
        sA[c * ZS + t * 32 + pv] = (__bf16)0.0f;
    }
    __bf16* zdst = (wave < 4) ? sB : sA;
    #pragma unroll
    for (int n4 = 0; n4 < 4; ++n4) {
      const int col = n4 * 16 + lr;
      const int v = col & 31;
      if (v < V_) {
        #pragma unroll
        for (int m2 = 0; m2 < 2; ++m2) {
          const int obase = (wave * 2 + m2) * 16 + lg * 4;
          #pragma unroll
          for (int r = 0; r < 4; ++r) {
            const int o = obase + r;
            float a = acc[m2][n4][r] + sB1a[o];
            float z = fmaf(gelu_exact(a), sInv[o], sAdd[o]);
            zdst[(o & 127) * ZS + col] = (__bf16)z;
          }
        }
      }
    }
  }
  __syncthreads();   // (3)

  // ---------------- P2: spatial mixing via MFMA ----------------
  float yv[2][2][4];   // [mt][t][r]
  const int h2 = wave >> 1, ch = wave & 1;
  const int cbase = h2 * 32 + ch * 16;
  {
    bf16x8 at[2], as2[2];
    #pragma unroll
    for (int mt = 0; mt < 2; ++mt) {
      at[mt]  = *reinterpret_cast<const bf16x8*>(Sp + (((h2 * 2 + 0) * 2 + mt) << 9) + lane * 8);
      as2[mt] = *reinterpret_cast<const bf16x8*>(Sp + (((h2 * 2 + 1) * 2 + mt) << 9) + lane * 8);
    }
    f32x4 accY[2][2] = {}, accA[2][2] = {};
    #pragma unroll
    for (int t = 0; t < 2; ++t) {
      bf16x8 bz1 = *reinterpret_cast<const bf16x8*>(&sB[(cbase + lr) * ZS + t * 32 + lg * 8]);
      bf16x8 bz2 = *reinterpret_cast<const bf16x8*>(&sA[(cbase + lr) * ZS + t * 32 + lg * 8]);
      #pragma unroll
      for (int mt = 0; mt < 2; ++mt) {
        accY[mt][t] = __builtin_amdgcn_mfma_f32_16x16x32_bf16(at[mt],  bz1, accY[mt][t], 0, 0, 0);
        accA[mt][t] = __builtin_amdgcn_mfma_f32_16x16x32_bf16(as2[mt], bz2, accA[mt][t], 0, 0, 0);
      }
    }
    const int c = cbase + lr;
    #pragma unroll
    for (int mt = 0; mt < 2; ++mt)
      #pragma unroll
      for (int t = 0; t < 2; ++t)
        #pragma unroll
        for (int r = 0; r < 4; ++r) {
          const int u = mt * 16 + lg * 4 + r;
          float z1u = (u < V_) ? (float)sB[c * ZS + t * 32 + u] : 0.0f;
          yv[mt][t][r] = fmaf(z1u, accA[mt][t][r], accY[mt][t][r]);
        }
  }
  __syncthreads();   // (4) — all z1 reads done; sB reusable as yT

  // ---------------- P2 store: yT -> sB (+ zero its pad rows) ----------------
  {
    for (int i = tid; i < 238; i += 512) {
      int rowIdx = i / 17, k = i - rowIdx * 17;
      int row = (rowIdx < 7 ? 25 + rowIdx : 50 + rowIdx);
      bf16x8 zz = {};
      *reinterpret_cast<bf16x8*>(sB + row * HS + k * 8) = zz;
    }
    const int c = cbase + lr;
    #pragma unroll
    for (int mt = 0; mt < 2; ++mt)
      #pragma unroll
      for (int t = 0; t < 2; ++t)
        #pragma unroll
        for (int r = 0; r < 4; ++r) {
          const int u = mt * 16 + lg * 4 + r;
          if (u < V_) sB[(t * 32 + u) * HS + c] = (__bf16)yv[mt][t][r];
        }
  }
  __syncthreads();   // (5)

  // ---------------- P3: conv2 MFMA (M=128,K=128,N=64) + residual + ReLU ----------------
  {
    f32x4 acc2[4] = {};
    #pragma unroll
    for (int ks = 0; ks < 4; ++ks) {
      bf16x8 af = *reinterpret_cast<const bf16x8*>(W2p + ((wave * 4 + ks) << 9) + lane * 8);
      #pragma unroll
      for (int n4 = 0; n4 < 4; ++n4) {
        bf16x8 bfr = *reinterpret_cast<const bf16x8*>(&sB[(n4 * 16 + lr) * HS + ks * 32 + lg * 8]);
        acc2[n4] = __builtin_amdgcn_mfma_f32_16x16x32_bf16(af, bfr, acc2[n4], 0, 0, 0);
      }
    }
    #pragma unroll
    for (int n4 = 0; n4 < 4; ++n4) {
      const int col = n4 * 16 + lr;
      const int u = col & 31, t = col >> 5;
      if (u < V_) {
        #pragma unroll
        for (int r = 0; r < 4; ++r) {
          const int o = wave * 16 + lg * 4 + r;
          const int off = o * TV + t * V_ + u;
          float val = acc2[n4][r] + sB2[o] + xb[off];
          ob[off] = fmaxf(val, 0.0f);
        }
      }
    }
  }
}

extern "C" void kernel_launch(void* const* d_in, const int* in_sizes, int n_in,
                              void* d_out, int out_size, void* d_ws, size_t ws_size,
                              hipStream_t stream) {
  const float* x    = (const float*)d_in[0];
  const float* bn0g = (const float*)d_in[1];
  const float* bn0b = (const float*)d_in[2];
  const float* bn0m = (const float*)d_in[3];
  const float* bn0v = (const float*)d_in[4];
  const float* W1   = (const float*)d_in[5];
  const float* b1   = (const float*)d_in[6];
  const float* bn1g = (const float*)d_in[7];
  const float* bn1b = (const float*)d_in[8];
  const float* bn1m = (const float*)d_in[9];
  const float* bn1v = (const float*)d_in[10];
  const float* bn2g = (const float*)d_in[11];
  const float* bn2b = (const float*)d_in[12];
  const float* bn2m = (const float*)d_in[13];
  const float* bn2v = (const float*)d_in[14];
  const float* topo = (const float*)d_in[15];
  const float* spat = (const float*)d_in[16];
  const float* W2   = (const float*)d_in[17];
  const float* b2   = (const float*)d_in[18];
  float* out = (float*)d_out;

  __bf16* W1p = (__bf16*)d_ws;            // 32768 elems (65536 B)
  __bf16* W2p = W1p + 32768;              // 16384 elems (32768 B)
  __bf16* Sp  = W2p + 16384;              //  8192 elems (16384 B)
  float*  b1a = (float*)((char*)d_ws + 114688);  // 256 f32

  prep_pack<<<129, 256, 0, stream>>>(W1, W2, topo, spat, b1,
                                     bn0g, bn0b, bn0m, bn0v,
                                     W1p, W2p, Sp, b1a);
  fused_v5<<<4096, 512, 0, stream>>>(
      x, bn1g, bn1b, bn1m, bn1v, bn2g, bn2b, bn2m, bn2v,
      b2, W1p, W2p, Sp, b1a, out);
}